// Round 2
// baseline (719.303 us; speedup 1.0000x reference)
//
#include <hip/hip_runtime.h>
#include <math.h>

// Problem constants: x (64,32,32,64) fp32 -> N=65536 rows of D=64; codebook K=1024.
#define NROWS 65536
#define KC 1024
#define DD 64
#define ROWS_PER_BLOCK 64
#define TR 16          // rows per tile
#define CK 128         // codebook cols per LDS chunk
#define NCH 8          // 1024/128
#define NT 4           // tiles per block
#define PX 68          // xs row pad (floats) — 16B aligned rows, 2-way max bank alias
#define PC 68          // cbs row pad (floats) — 16B aligned rows; stride-4 col map -> 4 disjoint quads

// ws layout (floats):
//  [0,1024)                      h_k = 0.5*||c_k||^2
//  [1024, 1024+1024*1024)        per-block avg_prob partials [block][k]
//  [WS_ACC, +4)                  accumulators: sqerr, ent_sum, avg_entropy
#define WS_H 0
#define WS_PART 1024
#define WS_ACC (1024 + 1024*1024)

// d_out layout (floats): quantized_st [0,4194304), loss [4194304], indices [4194305, ...)
#define LOSSOFF 4194304
#define IDXOFF  4194305

__global__ void vq_k0(const float* __restrict__ cb, float* __restrict__ ws) {
  int k = blockIdx.x * 256 + threadIdx.x;              // grid 4 x 256 -> k < 1024
  const float4* row = (const float4*)(cb + (k << 6));
  float s = 0.f;
  #pragma unroll
  for (int i = 0; i < 16; ++i) {
    float4 v = row[i];
    s += v.x * v.x + v.y * v.y + v.z * v.z + v.w * v.w;
  }
  ws[WS_H + k] = 0.5f * s;
  if (blockIdx.x == 0 && threadIdx.x < 4) ws[WS_ACC + threadIdx.x] = 0.f;
}

// Main fused kernel: distances (as z' = 200*(x.c - 0.5*||c||^2)), online softmax
// stats, argmax, prob accumulation, quantized output, latent-loss partials.
__launch_bounds__(256, 3)
__global__ void vq_k1(const float* __restrict__ x, const float* __restrict__ cb,
                      float* __restrict__ out, float* __restrict__ ws) {
  __shared__ float xs[TR][PX];
  __shared__ float cbs[CK][PC];
  __shared__ float hs[KC];
  __shared__ float avgp[KC];
  __shared__ float redM[4][16];
  __shared__ float redL[4][16];
  __shared__ float redS[4][16];
  __shared__ float redBV[4][16];
  __shared__ int   redBI[4][16];
  __shared__ float lseArr[16];
  __shared__ int   bestArr[16];
  __shared__ float entAcc;
  __shared__ float redQ[4];

  const int tid  = threadIdx.x;
  const int w    = tid >> 6;       // wave 0..3
  const int lane = tid & 63;
  const int r    = lane & 15;      // row within tile
  const int g    = lane >> 4;      // col subgroup 0..3
  const int cb0  = (w << 5) + g;   // col base within chunk; thread cols = cb0 + 4*j

  ((float4*)hs)[tid]   = ((const float4*)(ws + WS_H))[tid];
  ((float4*)avgp)[tid] = make_float4(0.f, 0.f, 0.f, 0.f);
  if (tid == 0) entAcc = 0.f;

  float sqAcc = 0.f;
  const int brow = blockIdx.x * ROWS_PER_BLOCK;

  #pragma unroll 1
  for (int tile = 0; tile < NT; ++tile) {
    const int row0 = brow + tile * TR;
    __syncthreads();   // protects xs/cbs/avgp/hs from previous-tile readers (or init)
    {
      const int xr = tid >> 4, xd = (tid & 15) << 2;
      *(float4*)&xs[xr][xd] = *(const float4*)(x + ((row0 + xr) << 6) + xd);
    }

    float zb[64];      // this thread's full row slice: col = (i>>3)*128 + cb0 + 4*(i&7)

    #pragma unroll
    for (int ch = 0; ch < NCH; ++ch) {
      if (ch > 0) __syncthreads();           // cbs consumers of ch-1 done
      #pragma unroll
      for (int u = 0; u < 8; ++u) {
        const int idx = (u << 8) + tid;      // 0..2047 float4s
        const int kr = idx >> 4, kd = (idx & 15) << 2;
        *(float4*)&cbs[kr][kd] = *(const float4*)(cb + (((ch << 7) + kr) << 6) + kd);
      }
      __syncthreads();                       // cbs (and xs on ch==0) ready

      #pragma unroll
      for (int j = 0; j < 8; ++j)
        zb[(ch << 3) + j] = -hs[(ch << 7) + cb0 + (j << 2)];

      #pragma unroll
      for (int dq = 0; dq < 16; ++dq) {
        const float4 xv = *(const float4*)&xs[r][dq << 2];
        #pragma unroll
        for (int j = 0; j < 8; ++j) {
          const float4 cv = *(const float4*)&cbs[cb0 + (j << 2)][dq << 2];
          float acc = zb[(ch << 3) + j];
          acc += xv.x * cv.x;
          acc += xv.y * cv.y;
          acc += xv.z * cv.z;
          acc += xv.w * cv.w;
          zb[(ch << 3) + j] = acc;
        }
      }
      #pragma unroll
      for (int j = 0; j < 8; ++j)
        zb[(ch << 3) + j] *= 200.f;          // z' = 200*(dot - 0.5*||c||^2)
    }

    // ---- row max ----
    float m = -INFINITY;
    #pragma unroll
    for (int i = 0; i < 64; ++i) m = fmaxf(m, zb[i]);
    m = fmaxf(m, __shfl_xor(m, 16));
    m = fmaxf(m, __shfl_xor(m, 32));
    if (g == 0) redM[w][r] = m;
    __syncthreads();
    m = fmaxf(fmaxf(redM[0][r], redM[1][r]), fmaxf(redM[2][r], redM[3][r]));

    // ---- sumexp, sum(exp*z), argmax ----
    float l = 0.f, s = 0.f, bv = -INFINITY;
    int bi = 0x7FFFFFFF;
    #pragma unroll
    for (int i = 0; i < 64; ++i) {
      const float zi = zb[i];
      const float u = __expf(zi - m);
      l += u;
      s += u * zi;
      const int col = ((i >> 3) << 7) + cb0 + ((i & 7) << 2);
      if (zi > bv || (zi == bv && col < bi)) { bv = zi; bi = col; }
    }
    #pragma unroll
    for (int mk = 16; mk <= 32; mk <<= 1) {
      l += __shfl_xor(l, mk);
      s += __shfl_xor(s, mk);
      const float obv = __shfl_xor(bv, mk);
      const int   obi = __shfl_xor(bi, mk);
      if (obv > bv || (obv == bv && obi < bi)) { bv = obv; bi = obi; }
    }
    if (g == 0) { redL[w][r] = l; redS[w][r] = s; redBV[w][r] = bv; redBI[w][r] = bi; }
    __syncthreads();
    if (tid < 16) {                          // one finalizer per row (r == tid)
      float L = 0.f, S = 0.f, BV = -INFINITY;
      int BI = 0x7FFFFFFF;
      #pragma unroll
      for (int wv = 0; wv < 4; ++wv) {
        L += redL[wv][tid];
        S += redS[wv][tid];
        const float v = redBV[wv][tid];
        const int  ix = redBI[wv][tid];
        if (v > BV || (v == BV && ix < BI)) { BV = v; BI = ix; }
      }
      const float lse = m + __logf(L);
      lseArr[tid] = lse;
      bestArr[tid] = BI;
      atomicAdd(&entAcc, lse - S / L);       // per-row sample entropy
      out[IDXOFF + row0 + tid] = (float)BI;
    }
    __syncthreads();

    // ---- prob accumulation into per-block partials (no atomics: unique col owner) ----
    const float lse = lseArr[r];
    #pragma unroll
    for (int i = 0; i < 64; ++i) {
      float p = __expf(zb[i] - lse);
      p += __shfl_xor(p, 1);
      p += __shfl_xor(p, 2);
      p += __shfl_xor(p, 4);
      p += __shfl_xor(p, 8);                 // sum over the 16 rows
      if (r == 0) {
        const int col = ((i >> 3) << 7) + cb0 + ((i & 7) << 2);
        avgp[col] += p;
      }
    }

    // ---- quantized output + squared-error partial ----
    {
      const int qr = tid >> 4, qd = (tid & 15) << 2;
      const int code = bestArr[qr];
      const float4 c4 = *(const float4*)(cb + (code << 6) + qd);
      const float4 x4 = *(const float4*)&xs[qr][qd];
      const float dx = c4.x - x4.x, dy = c4.y - x4.y, dz = c4.z - x4.z, dw = c4.w - x4.w;
      sqAcc += dx * dx + dy * dy + dz * dz + dw * dw;
      float4 o;                              // mimic x + (q - x) like the reference
      o.x = x4.x + dx; o.y = x4.y + dy; o.z = x4.z + dz; o.w = x4.w + dw;
      *(float4*)(out + ((row0 + qr) << 6) + qd) = o;
    }
  }

  __syncthreads();
  ((float4*)(ws + WS_PART + (blockIdx.x << 10)))[tid] = ((float4*)avgp)[tid];

  #pragma unroll
  for (int mk = 1; mk <= 32; mk <<= 1) sqAcc += __shfl_xor(sqAcc, mk);
  if (lane == 0) redQ[w] = sqAcc;
  __syncthreads();
  if (tid == 0) {
    atomicAdd(ws + WS_ACC + 0, redQ[0] + redQ[1] + redQ[2] + redQ[3]);
    atomicAdd(ws + WS_ACC + 1, entAcc);
  }
}

// Reduce per-block partials -> avg_probs -> avg_entropy contribution.
__global__ void vq_k2(float* __restrict__ ws) {
  __shared__ float sh[8][32];
  const int t = threadIdx.x;
  const int bl = t >> 5, cl = t & 31;
  const int k = blockIdx.x * 32 + cl;       // grid 32 -> k < 1024
  float s = 0.f;
  #pragma unroll 4
  for (int i = 0; i < 128; ++i)
    s += ws[WS_PART + ((bl << 7) + i) * 1024 + k];
  sh[bl][cl] = s;
  __syncthreads();
  if (t < 32) {
    float tot = 0.f;
    #pragma unroll
    for (int b = 0; b < 8; ++b) tot += sh[b][t];
    const float p = tot * (1.f / 65536.f);
    float c = -p * __logf(p + 1e-5f);
    c += __shfl_xor(c, 1);
    c += __shfl_xor(c, 2);
    c += __shfl_xor(c, 4);
    c += __shfl_xor(c, 8);
    c += __shfl_xor(c, 16);
    if (t == 0) atomicAdd(ws + WS_ACC + 2, c);
  }
}

__global__ void vq_k3(const float* __restrict__ ws, float* __restrict__ out) {
  if (threadIdx.x == 0) {
    const float msq  = ws[WS_ACC + 0] * (1.f / (65536.f * 64.f));
    const float sent = ws[WS_ACC + 1] * (1.f / 65536.f);
    const float aent = ws[WS_ACC + 2];
    // (0.25 + 1.0) * mean((q-x)^2) + 0.1 * (sample_entropy - avg_entropy)
    out[LOSSOFF] = 1.25f * msq + 0.1f * (sent - aent);
  }
}

extern "C" void kernel_launch(void* const* d_in, const int* in_sizes, int n_in,
                              void* d_out, int out_size, void* d_ws, size_t ws_size,
                              hipStream_t stream) {
  (void)in_sizes; (void)n_in; (void)out_size; (void)ws_size;
  const float* x  = (const float*)d_in[0];
  const float* cb = (const float*)d_in[1];
  float* out = (float*)d_out;
  float* ws  = (float*)d_ws;

  vq_k0<<<dim3(4),    dim3(256), 0, stream>>>(cb, ws);
  vq_k1<<<dim3(1024), dim3(256), 0, stream>>>(x, cb, out, ws);
  vq_k2<<<dim3(32),   dim3(256), 0, stream>>>(ws);
  vq_k3<<<dim3(1),    dim3(64),  0, stream>>>(ws, out);
}